// Round 11
// baseline (17800.690 us; speedup 1.0000x reference)
//
#include <hip/hip_runtime.h>
#include <math.h>

// Problem constants (fixed by the reference)
#define NV 20000
#define NH 512
#define NT 1024
#define NB 32
#define MAXD 64

// LSTM persistent-kernel geometry (1024-thread blocks: per-thread gate_w
// slice is 64 floats and fits the 128-VGPR/thread cap of 16-wave blocks.
// R9's 128-float slice could not fit -> suspected per-step gate_w refetch,
// the ~20 GB/launch FETCH term).
#define NGRP 8      // groups (independent batch-row sets); sync domain = 1 group
#define BPG 32      // blocks per group
#define BPB 4       // batch rows per group  (NB / NGRP)
#define UPB 16      // hidden units per block (NH / BPG)
#define NJ 64       // gate rows per block = 4*UPB
#define KTOT 1024   // 2*NH
#define NTH 1024
#define KS_N 64     // k-slices per block
#define KHALF 8     // k elements per thread per half (x-half + h-half = 16)

typedef int v4i __attribute__((ext_vector_type(4)));

// ws layout: [ path: NV*NH f32 | hbuf: 2*NB*NH f32 | prog: 256 ints ] ~= 41.1 MB

__global__ void init_kernel(float* __restrict__ hbuf, int* __restrict__ prog) {
  int i = blockIdx.x * blockDim.x + threadIdx.x;
  if (i < 2 * NB * NH)
    __hip_atomic_store(&hbuf[i], 0.f, __ATOMIC_RELAXED, __HIP_MEMORY_SCOPE_SYSTEM);
  if (i < 256)
    __hip_atomic_store(&prog[i], 0, __ATOMIC_RELAXED, __HIP_MEMORY_SCOPE_SYSTEM);
}

// One block per node: all 256 threads walk the same parent chain (uniform),
// each thread accumulates 2 of the 512 embedding columns (coalesced).
__global__ __launch_bounds__(256)
void path_kernel(const int* __restrict__ parents,
                 const float* __restrict__ weight,
                 const float* __restrict__ emb,
                 float* __restrict__ path) {
  int v = blockIdx.x;
  int h = threadIdx.x;
  float acc0 = 0.f, acc1 = 0.f;
  float w = 1.f;
  int cur = v;
#pragma unroll 1
  for (int d = 0; d < MAXD; ++d) {
    if (cur < 0) break;
    const float* row = emb + (size_t)cur * NH;
    acc0 = fmaf(w, row[h], acc0);
    acc1 = fmaf(w, row[h + 256], acc1);
    w *= weight[cur];
    cur = parents[cur];
  }
  path[(size_t)v * NH + h] = acc0;
  path[(size_t)v * NH + h + 256] = acc1;
}

// f(k) = k + k/32 : +1 dword pad per 32 -> conflict-free LDS columns
__device__ __forceinline__ int fpad(int k) { return k + (k >> 5); }

// Persistent LSTM: 256 blocks = 8 groups x 32 blocks, 1 block/CU, 1024 thr.
// Cross-block data (hbuf, prog) via sc0 sc1 cache-bypass accesses; everything
// else L2-cached; no cache-wide fences. Producer: h stores -> wave-level
// vmcnt(0) -> prog[blk]=t+1 (no RMW). Consumer poll: 8 lanes x dwordx4
// (load+waitcnt fused in ONE asm -> result fully defined at asm exit, safe).
// h staging (R11 fix): compiler-visible 2x 8B system-scope atomic loads per
// stager thread -- the R10 split-asm load could be spilled/copied by the
// register allocator BEFORE the hand-placed vmcnt (asm hides the dependency),
// storing garbage under the 128-VGPR pressure of 16-wave blocks -> NaN.
__global__ __launch_bounds__(NTH, 1)
void lstm_kernel(const int* __restrict__ ev,
                 const float* __restrict__ path,
                 const float* __restrict__ gate_w,
                 const float* __restrict__ gate_b,
                 float* __restrict__ hbuf,   // [2][NB][NH]
                 int* __restrict__ prog,     // [NGRP][BPG] per-producer step ctr
                 float* __restrict__ out) {  // [3][NT][NB][NH]
  __shared__ float in_s[BPB][KTOT + KTOT / 32];   // [x(t) | h(t)] padded
  __shared__ float p_s[KS_N][NJ * BPB + 1];       // stride 257 -> conflict-free
  __shared__ float zred[NJ * BPB];
  __shared__ float c_s[BPB][UPB];

  const int bid = blockIdx.x;
  const int grp = bid & 7;
  const int blk = bid >> 3;
  const int b0 = grp * BPB;
  const int u0 = blk * UPB;
  const int tid = threadIdx.x;
  const int jg = tid >> 6;   // 0..15: which 4-row group of gate rows
  const int ks = tid & 63;   // 0..63: which k-slice (8 x-k + 8 h-k)

  // gate_w slice in registers for all 1024 steps (64 floats/thread):
  // w[jj][0..7]  = W[j][ks*8 .. +8)          (x half)
  // w[jj][8..15] = W[j][512 + ks*8 .. +8)    (h half)
  float w[4][2 * KHALF];
#pragma unroll
  for (int jj = 0; jj < 4; ++jj) {
    int r = jg * 4 + jj;                        // 0..63: gate*16 + uu
    int j = (r >> 4) * NH + u0 + (r & 15);      // global gate row
    const float* wx = gate_w + (size_t)j * KTOT + ks * KHALF;
    const float* wh = gate_w + (size_t)j * KTOT + NH + ks * KHALF;
#pragma unroll
    for (int kk = 0; kk < KHALF; ++kk) {
      w[jj][kk] = wx[kk];
      w[jj][KHALF + kk] = wh[kk];
    }
  }

  if (tid < BPB * UPB) c_s[tid >> 4][tid & 15] = 0.f;

  // staging map (first 512 threads): thread -> (row sb2, 4-float chunk off4)
  const int sb2 = (tid >> 7) & 3;    // 0..3
  const int off4 = (tid & 127) * 4;  // 0..508
  const bool stager = tid < 512;
  const size_t plane = (size_t)NT * NB * NH;
  int* myprog = prog + grp * BPG + blk;
  const int* pollp4 = prog + grp * BPG + (tid & 7) * 4;

  // pre-stage x(0) (cached loads; visibility via barrier A0 at t=0)
  if (stager) {
    int e = ev[0 * NB + b0 + sb2];
    float4 v0 = *(const float4*)(path + (size_t)e * NH + off4);
    *(float4*)&in_s[sb2][fpad(off4)] = v0;
  }

#pragma unroll 1
  for (int t = 0; t < NT; ++t) {
    const bool more = (t + 1 < NT);

    // ---- wait for group's h(t) producers: 8 lanes x dwordx4 ----
    if (t > 0 && tid < 8) {
      v4i pv;
      for (;;) {
        asm volatile("global_load_dwordx4 %0, %1, off sc0 sc1\n\ts_waitcnt vmcnt(0)"
                     : "=v"(pv) : "v"(pollp4) : "memory");
        bool ok = (pv[0] >= t) && (pv[1] >= t) && (pv[2] >= t) && (pv[3] >= t);
        if ((__ballot(ok) & 0xFFull) == 0xFFull) break;
        __builtin_amdgcn_s_sleep(1);
      }
    }
    __syncthreads();   // A0: poll passed; prev step's LDS reads all complete

    // ---- issue h(t) bypass loads (2x 8B atomic loads, compiler-visible;
    //      issued here so they overlap the x-half GEMM below) ----
    double hd0 = 0.0, hd1 = 0.0;
    if (stager) {
      const double* hsrc = (const double*)(
          hbuf + ((size_t)(t & 1) * NB + (b0 + sb2)) * NH + off4);
      hd0 = __hip_atomic_load(hsrc, __ATOMIC_RELAXED, __HIP_MEMORY_SCOPE_SYSTEM);
      hd1 = __hip_atomic_load(hsrc + 1, __ATOMIC_RELAXED, __HIP_MEMORY_SCOPE_SYSTEM);
    }

    // ---- x-half GEMM: k in [ks*8, ks*8+8) from in_s x-half ----
    float acc[4][BPB];
#pragma unroll
    for (int jj = 0; jj < 4; ++jj)
#pragma unroll
      for (int bi = 0; bi < BPB; ++bi) acc[jj][bi] = 0.f;
    {
      const int fb = fpad(ks * KHALF);
#pragma unroll
      for (int bi = 0; bi < BPB; ++bi) {
        const float* inp = &in_s[bi][fb];
#pragma unroll
        for (int kk = 0; kk < KHALF; ++kk) {
          float x = inp[kk];
          acc[0][bi] = fmaf(w[0][kk], x, acc[0][bi]);
          acc[1][bi] = fmaf(w[1][kk], x, acc[1][bi]);
          acc[2][bi] = fmaf(w[2][kk], x, acc[2][bi]);
          acc[3][bi] = fmaf(w[3][kk], x, acc[3][bi]);
        }
      }
    }

    // ---- h arrived: write to LDS h-half (compiler inserts the vmcnt) ----
    if (stager) {
      float2 f0 = __builtin_bit_cast(float2, hd0);
      float2 f1 = __builtin_bit_cast(float2, hd1);
      float* d = &in_s[sb2][fpad(NH + off4)];
      *(float2*)(d + 0) = f0;
      *(float2*)(d + 2) = f1;
    }
    __syncthreads();   // A1: h(t) staged

    // ---- h-half GEMM: k in [512 + ks*8, +8) ----
    {
      const int fb = fpad(NH + ks * KHALF);
#pragma unroll
      for (int bi = 0; bi < BPB; ++bi) {
        const float* inp = &in_s[bi][fb];
#pragma unroll
        for (int kk = 0; kk < KHALF; ++kk) {
          float x = inp[kk];
          acc[0][bi] = fmaf(w[0][KHALF + kk], x, acc[0][bi]);
          acc[1][bi] = fmaf(w[1][KHALF + kk], x, acc[1][bi]);
          acc[2][bi] = fmaf(w[2][KHALF + kk], x, acc[2][bi]);
          acc[3][bi] = fmaf(w[3][KHALF + kk], x, acc[3][bi]);
        }
      }
    }
#pragma unroll
    for (int jj = 0; jj < 4; ++jj) {
      int r = jg * 4 + jj;
#pragma unroll
      for (int bi = 0; bi < BPB; ++bi)
        p_s[ks][r * BPB + bi] = acc[jj][bi];
    }
    __syncthreads();   // B: p_s complete; in_s x-half dead

    // ---- prefetch x(t+1) into in_s x-half (cached; off critical path) ----
    if (more && stager) {
      int e = ev[(t + 1) * NB + b0 + sb2];
      float4 v0 = *(const float4*)(path + (size_t)e * NH + off4);
      *(float4*)&in_s[sb2][fpad(off4)] = v0;
    }

    // ---- reduce 64 k-slices + bias (first 256 threads) ----
    if (tid < NJ * BPB) {
      float s = 0.f;
#pragma unroll
      for (int k2 = 0; k2 < KS_N; ++k2) s += p_s[k2][tid];
      int r = tid >> 2;
      s += gate_b[(r >> 4) * NH + u0 + (r & 15)];
      zred[tid] = s;
    }
    __syncthreads();   // C: zred complete

    // ---- gates + state update + handoff (wave 0 only) ----
    if (tid < BPB * UPB) {
      int bi = tid >> 4, uu = tid & 15;
      float zi = zred[(uu) * BPB + bi];
      float zf = zred[(UPB + uu) * BPB + bi];
      float zg = zred[(2 * UPB + uu) * BPB + bi];
      float zo = zred[(3 * UPB + uu) * BPB + bi];
      float ig = 1.f / (1.f + expf(-zi));
      float fg = 1.f / (1.f + expf(-zf));
      float gg = tanhf(zg);
      float ogv = 1.f / (1.f + expf(-zo));
      float cv = fmaf(fg, c_s[bi][uu], ig * gg);
      float hvv = ogv * tanhf(cv);
      c_s[bi][uu] = cv;
      int b = b0 + bi, u = u0 + uu;
      if (more) {
        float* hdst = hbuf + ((size_t)((t + 1) & 1) * NB + b) * NH + u;
        __hip_atomic_store(hdst, hvv, __ATOMIC_RELAXED, __HIP_MEMORY_SCOPE_SYSTEM);
      }
      // announce: wave-level drain of the h stores, then per-producer word
      if (more && tid == 0) {
        asm volatile("s_waitcnt vmcnt(0)" ::: "memory");
        int nv = t + 1;
        asm volatile("global_store_dword %0, %1, off sc0 sc1"
                     :: "v"(myprog), "v"(nv) : "memory");
      }
      // output stores off the critical path (after the signal)
      size_t o0 = ((size_t)t * NB + b) * NH + u;
      out[o0] = hvv;
      out[plane + o0] = cv;
      out[2 * plane + o0] = ogv;
    }
    // no end-of-step barrier: next iteration's poll + A0 covers it
  }
}

extern "C" void kernel_launch(void* const* d_in, const int* in_sizes, int n_in,
                              void* d_out, int out_size, void* d_ws, size_t ws_size,
                              hipStream_t stream) {
  const int* ev = (const int*)d_in[0];
  const int* parents = (const int*)d_in[1];
  const float* weight = (const float*)d_in[2];
  const float* emb = (const float*)d_in[3];
  const float* gate_w = (const float*)d_in[4];
  const float* gate_b = (const float*)d_in[5];
  float* out = (float*)d_out;

  char* ws = (char*)d_ws;
  float* path = (float*)ws;
  size_t path_bytes = (size_t)NV * NH * sizeof(float);
  float* hbuf = (float*)(ws + path_bytes);
  int* prog = (int*)(ws + path_bytes + (size_t)2 * NB * NH * sizeof(float));

  init_kernel<<<(2 * NB * NH + 255) / 256, 256, 0, stream>>>(hbuf, prog);
  path_kernel<<<NV, 256, 0, stream>>>(parents, weight, emb, path);
  lstm_kernel<<<NGRP * BPG, NTH, 0, stream>>>(ev, path, gate_w, gate_b, hbuf, prog, out);
}

// Round 12
// 12838.617 us; speedup vs baseline: 1.3865x; 1.3865x over previous
//
#include <hip/hip_runtime.h>
#include <math.h>

// Problem constants (fixed by the reference)
#define NV 20000
#define NH 512
#define NT 1024
#define NB 32
#define MAXD 64

// LSTM persistent-kernel geometry
#define NGRP 8      // groups (independent batch-row sets); sync domain = 1 group
#define BPG 32      // blocks per group
#define BPB 4       // batch rows per group  (NB / NGRP)
#define UPB 16      // hidden units per block (NH / BPG)
#define NJ 64       // gate rows per block = 4*UPB
#define KTOT 1024   // 2*NH
#define NTH 512
#define KHALF 16    // k elements per thread per half (x-half + h-half = 32)

typedef int v4i __attribute__((ext_vector_type(4)));

// ws layout: [ path: NV*NH f32 | hbuf: 2*NB*NH f32 | prog: 256 ints ] ~= 41.1 MB

__global__ void init_kernel(float* __restrict__ hbuf, int* __restrict__ prog) {
  int i = blockIdx.x * blockDim.x + threadIdx.x;
  if (i < 2 * NB * NH)
    __hip_atomic_store(&hbuf[i], 0.f, __ATOMIC_RELAXED, __HIP_MEMORY_SCOPE_SYSTEM);
  if (i < 256)
    __hip_atomic_store(&prog[i], 0, __ATOMIC_RELAXED, __HIP_MEMORY_SCOPE_SYSTEM);
}

// One block per node: all 256 threads walk the same parent chain (uniform),
// each thread accumulates 2 of the 512 embedding columns (coalesced).
__global__ __launch_bounds__(256)
void path_kernel(const int* __restrict__ parents,
                 const float* __restrict__ weight,
                 const float* __restrict__ emb,
                 float* __restrict__ path) {
  int v = blockIdx.x;
  int h = threadIdx.x;
  float acc0 = 0.f, acc1 = 0.f;
  float w = 1.f;
  int cur = v;
#pragma unroll 1
  for (int d = 0; d < MAXD; ++d) {
    if (cur < 0) break;
    const float* row = emb + (size_t)cur * NH;
    acc0 = fmaf(w, row[h], acc0);
    acc1 = fmaf(w, row[h + 256], acc1);
    w *= weight[cur];
    cur = parents[cur];
  }
  path[(size_t)v * NH + h] = acc0;
  path[(size_t)v * NH + h + 256] = acc1;
}

// f(k) = k + k/32 : +1 dword pad per 32 -> conflict-free LDS columns
__device__ __forceinline__ int fpad(int k) { return k + (k >> 5); }

// Persistent LSTM: 256 blocks, 512 thr (R9-verified structure).
// R12 change (ONLY): group/block decode swapped to grp=bid>>5, blk=bid&31.
// With round-robin block->XCD dispatch, XCD x now hosts blk in
// {x, x+8, x+16, x+24} for all 8 groups = 4 distinct gate_w slices = 1 MB,
// fully L2-resident. (R9's grp=bid&7 put 32 DISTINCT slices = 8 MB on each
// XCD's 4 MB L2 -> per-step gate_w re-loads -- which the compiler emits, it
// never keeps w[] in VGPRs (VGPR_Count=64..128 every round) -- all missed to
// HBM: the constant ~20-40 GB FETCH term, dur ~ FETCH/2TB/s in R3..R11.)
// Cross-block data (hbuf, prog) via sc0 sc1 bypass; no cache-wide fences.
__global__ __launch_bounds__(NTH, 1)
void lstm_kernel(const int* __restrict__ ev,
                 const float* __restrict__ path,
                 const float* __restrict__ gate_w,
                 const float* __restrict__ gate_b,
                 float* __restrict__ hbuf,   // [2][NB][NH]
                 int* __restrict__ prog,     // [NGRP][BPG] per-producer step ctr
                 float* __restrict__ out) {  // [3][NT][NB][NH]
  __shared__ float in_s[BPB][KTOT + KTOT / 32];   // [x(t) | h(t)] padded
  __shared__ float p_s[32][NJ * BPB + 1];         // stride 257 -> conflict-free
  __shared__ float zred[NJ * BPB];
  __shared__ float c_s[BPB][UPB];

  const int bid = blockIdx.x;
  const int grp = bid >> 5;   // R12: group = consecutive 32-block range
  const int blk = bid & 31;   // R12: same-blk blocks land on the same XCD
  const int b0 = grp * BPB;
  const int u0 = blk * UPB;
  const int tid = threadIdx.x;
  const int jg = tid >> 5;   // 0..15: which 4-row group of gate rows
  const int ks = tid & 31;   // 0..31: which k-slice (16 x-k + 16 h-k)

  // gate_w slice (the compiler will partially re-load this per step; with the
  // new mapping those re-loads are L2 hits):
  // w[jj][0..15]  = W[j][ks*16 .. +16)          (x half)
  // w[jj][16..31] = W[j][512 + ks*16 .. +16)    (h half)
  float w[4][2 * KHALF];
#pragma unroll
  for (int jj = 0; jj < 4; ++jj) {
    int r = jg * 4 + jj;                        // 0..63: gate*16 + uu
    int j = (r >> 4) * NH + u0 + (r & 15);      // global gate row
    const float* wx = gate_w + (size_t)j * KTOT + ks * KHALF;
    const float* wh = gate_w + (size_t)j * KTOT + NH + ks * KHALF;
#pragma unroll
    for (int kk = 0; kk < KHALF; ++kk) {
      w[jj][kk] = wx[kk];
      w[jj][KHALF + kk] = wh[kk];
    }
  }

  if (tid < BPB * UPB) c_s[tid >> 4][tid & 15] = 0.f;

  // staging map: thread -> (row sb2, 4-float chunk off4)
  const int sb2 = tid >> 7;          // 0..3
  const int off4 = (tid & 127) * 4;  // 0..508
  const size_t plane = (size_t)NT * NB * NH;
  int* myprog = prog + grp * BPG + blk;
  const int* pollp4 = prog + grp * BPG + (tid & 7) * 4;

  // pre-stage x(0) (cached loads; visibility via barrier A0 at t=0)
  {
    int e = ev[0 * NB + b0 + sb2];
    float4 v0 = *(const float4*)(path + (size_t)e * NH + off4);
    *(float4*)&in_s[sb2][fpad(off4)] = v0;
  }

#pragma unroll 1
  for (int t = 0; t < NT; ++t) {
    const bool more = (t + 1 < NT);

    // ---- wait for group's h(t) producers: 8 lanes x dwordx4 ----
    if (t > 0 && tid < 8) {
      v4i pv;
      for (;;) {
        asm volatile("global_load_dwordx4 %0, %1, off sc0 sc1\n\ts_waitcnt vmcnt(0)"
                     : "=v"(pv) : "v"(pollp4) : "memory");
        bool ok = (pv[0] >= t) && (pv[1] >= t) && (pv[2] >= t) && (pv[3] >= t);
        if ((__ballot(ok) & 0xFFull) == 0xFFull) break;
        __builtin_amdgcn_s_sleep(1);
      }
    }
    __syncthreads();   // A0: poll passed; prev step's LDS reads all complete

    // ---- issue h(t) bypass load (16B/thread), fly under x-half GEMM ----
    float4 hv;
    {
      const float* hsrc =
          hbuf + ((size_t)(t & 1) * NB + (b0 + sb2)) * NH + off4;
      asm volatile("global_load_dwordx4 %0, %1, off sc0 sc1"
                   : "=v"(hv) : "v"(hsrc) : "memory");
    }

    // ---- x-half GEMM: k in [ks*16, ks*16+16) from in_s x-half ----
    float acc[4][BPB];
#pragma unroll
    for (int jj = 0; jj < 4; ++jj)
#pragma unroll
      for (int bi = 0; bi < BPB; ++bi) acc[jj][bi] = 0.f;
    {
      const int fb = fpad(ks * KHALF);
#pragma unroll
      for (int bi = 0; bi < BPB; ++bi) {
        const float* inp = &in_s[bi][fb];
#pragma unroll
        for (int kk = 0; kk < KHALF; ++kk) {
          float x = inp[kk];
          acc[0][bi] = fmaf(w[0][kk], x, acc[0][bi]);
          acc[1][bi] = fmaf(w[1][kk], x, acc[1][bi]);
          acc[2][bi] = fmaf(w[2][kk], x, acc[2][bi]);
          acc[3][bi] = fmaf(w[3][kk], x, acc[3][bi]);
        }
      }
    }

    // ---- h arrived: drain the bypass load, then write to LDS h-half ----
    asm volatile("s_waitcnt vmcnt(0)" ::: "memory");
    __builtin_amdgcn_sched_barrier(0);
    *(float4*)&in_s[sb2][fpad(NH + off4)] = hv;
    __syncthreads();   // A1: h(t) staged

    // ---- h-half GEMM: k in [512 + ks*16, +16) ----
    {
      const int fb = fpad(NH + ks * KHALF);
#pragma unroll
      for (int bi = 0; bi < BPB; ++bi) {
        const float* inp = &in_s[bi][fb];
#pragma unroll
        for (int kk = 0; kk < KHALF; ++kk) {
          float x = inp[kk];
          acc[0][bi] = fmaf(w[0][KHALF + kk], x, acc[0][bi]);
          acc[1][bi] = fmaf(w[1][KHALF + kk], x, acc[1][bi]);
          acc[2][bi] = fmaf(w[2][KHALF + kk], x, acc[2][bi]);
          acc[3][bi] = fmaf(w[3][KHALF + kk], x, acc[3][bi]);
        }
      }
    }
#pragma unroll
    for (int jj = 0; jj < 4; ++jj) {
      int r = jg * 4 + jj;
#pragma unroll
      for (int bi = 0; bi < BPB; ++bi)
        p_s[ks][r * BPB + bi] = acc[jj][bi];
    }
    __syncthreads();   // B: p_s complete; in_s x-half dead

    // ---- prefetch x(t+1) into in_s x-half (cached; off critical path) ----
    if (more) {
      int e = ev[(t + 1) * NB + b0 + sb2];
      float4 v0 = *(const float4*)(path + (size_t)e * NH + off4);
      *(float4*)&in_s[sb2][fpad(off4)] = v0;
    }

    // ---- reduce 32 k-slices + bias ----
    if (tid < NJ * BPB) {
      float s = 0.f;
#pragma unroll
      for (int k2 = 0; k2 < 32; ++k2) s += p_s[k2][tid];
      int r = tid >> 2;
      s += gate_b[(r >> 4) * NH + u0 + (r & 15)];
      zred[tid] = s;
    }
    __syncthreads();   // C: zred complete

    // ---- gates + state update + handoff (wave 0 only) ----
    if (tid < BPB * UPB) {
      int bi = tid >> 4, uu = tid & 15;
      float zi = zred[(uu) * BPB + bi];
      float zf = zred[(UPB + uu) * BPB + bi];
      float zg = zred[(2 * UPB + uu) * BPB + bi];
      float zo = zred[(3 * UPB + uu) * BPB + bi];
      float ig = 1.f / (1.f + expf(-zi));
      float fg = 1.f / (1.f + expf(-zf));
      float gg = tanhf(zg);
      float ogv = 1.f / (1.f + expf(-zo));
      float cv = fmaf(fg, c_s[bi][uu], ig * gg);
      float hvv = ogv * tanhf(cv);
      c_s[bi][uu] = cv;
      int b = b0 + bi, u = u0 + uu;
      if (more) {
        float* hdst = hbuf + ((size_t)((t + 1) & 1) * NB + b) * NH + u;
        __hip_atomic_store(hdst, hvv, __ATOMIC_RELAXED, __HIP_MEMORY_SCOPE_SYSTEM);
      }
      // announce: wave-level drain of the h stores, then per-producer word
      if (more && tid == 0) {
        asm volatile("s_waitcnt vmcnt(0)" ::: "memory");
        int nv = t + 1;
        asm volatile("global_store_dword %0, %1, off sc0 sc1"
                     :: "v"(myprog), "v"(nv) : "memory");
      }
      // output stores off the critical path (after the signal)
      size_t o0 = ((size_t)t * NB + b) * NH + u;
      out[o0] = hvv;
      out[plane + o0] = cv;
      out[2 * plane + o0] = ogv;
    }
    // no end-of-step barrier: next iteration's poll + A0 covers it
  }
}

extern "C" void kernel_launch(void* const* d_in, const int* in_sizes, int n_in,
                              void* d_out, int out_size, void* d_ws, size_t ws_size,
                              hipStream_t stream) {
  const int* ev = (const int*)d_in[0];
  const int* parents = (const int*)d_in[1];
  const float* weight = (const float*)d_in[2];
  const float* emb = (const float*)d_in[3];
  const float* gate_w = (const float*)d_in[4];
  const float* gate_b = (const float*)d_in[5];
  float* out = (float*)d_out;

  char* ws = (char*)d_ws;
  float* path = (float*)ws;
  size_t path_bytes = (size_t)NV * NH * sizeof(float);
  float* hbuf = (float*)(ws + path_bytes);
  int* prog = (int*)(ws + path_bytes + (size_t)2 * NB * NH * sizeof(float));

  init_kernel<<<(2 * NB * NH + 255) / 256, 256, 0, stream>>>(hbuf, prog);
  path_kernel<<<NV, 256, 0, stream>>>(parents, weight, emb, path);
  lstm_kernel<<<NGRP * BPG, NTH, 0, stream>>>(ev, path, gate_w, gate_b, hbuf, prog, out);
}

// Round 13
// 12477.218 us; speedup vs baseline: 1.4267x; 1.0290x over previous
//
#include <hip/hip_runtime.h>
#include <math.h>

// Problem constants (fixed by the reference)
#define NV 20000
#define NH 512
#define NT 1024
#define NB 32
#define MAXD 64

// LSTM persistent-kernel geometry
#define NGRP 8      // groups (independent batch-row sets); sync domain = 1 group
#define BPG 32      // blocks per group
#define BPB 4       // batch rows per group  (NB / NGRP)
#define UPB 16      // hidden units per block (NH / BPG)
#define NJ 64       // gate rows per block = 4*UPB
#define KTOT 1024   // 2*NH
#define NTH 512
#define KHALF 16    // k elements per thread per half (x-half + h-half = 32)

typedef int v4i __attribute__((ext_vector_type(4)));

// ws layout: [ path: NV*NH f32 | hbuf: 2*NB*NH f32 | prog: 256 ints ] ~= 41.1 MB

__global__ void init_kernel(float* __restrict__ hbuf, int* __restrict__ prog) {
  int i = blockIdx.x * blockDim.x + threadIdx.x;
  if (i < 2 * NB * NH)
    __hip_atomic_store(&hbuf[i], 0.f, __ATOMIC_RELAXED, __HIP_MEMORY_SCOPE_SYSTEM);
  if (i < 256)
    __hip_atomic_store(&prog[i], 0, __ATOMIC_RELAXED, __HIP_MEMORY_SCOPE_SYSTEM);
}

// One block per node: all 256 threads walk the same parent chain (uniform),
// each thread accumulates 2 of the 512 embedding columns (coalesced).
__global__ __launch_bounds__(256)
void path_kernel(const int* __restrict__ parents,
                 const float* __restrict__ weight,
                 const float* __restrict__ emb,
                 float* __restrict__ path) {
  int v = blockIdx.x;
  int h = threadIdx.x;
  float acc0 = 0.f, acc1 = 0.f;
  float w = 1.f;
  int cur = v;
#pragma unroll 1
  for (int d = 0; d < MAXD; ++d) {
    if (cur < 0) break;
    const float* row = emb + (size_t)cur * NH;
    acc0 = fmaf(w, row[h], acc0);
    acc1 = fmaf(w, row[h + 256], acc1);
    w *= weight[cur];
    cur = parents[cur];
  }
  path[(size_t)v * NH + h] = acc0;
  path[(size_t)v * NH + h + 256] = acc1;
}

// f(k) = k + k/32 : +1 dword pad per 32 -> conflict-free LDS columns
__device__ __forceinline__ int fpad(int k) { return k + (k >> 5); }

// Persistent LSTM: 256 blocks = 8 groups x 32 blocks, 512 thr, 1 block/CU.
// Cross-block data (hbuf, prog) via sc0 sc1 cache-bypass accesses; everything
// else L2-cached; no cache-wide fences.
// R13: h staging = 128 stagers x 4 consecutive dwordx4 bypass loads (one
// 64B line per request -- bypass requests are never line-merged, so request
// count IS line count; R9's 512x16B did 4x the line fetches: the ~17GB/launch
// FETCH term). The 4 loads + s_waitcnt are fused in ONE asm block so the
// outputs are fully landed at asm exit -- no unlanded-register spill hazard
// (R8/R10 failure class); "=&v" early-clobber keeps outputs off the address
// register. Costs the x-GEMM overlap; h-load latency (~1us, 4-deep
// pipelined) is paid serially instead.
__global__ __launch_bounds__(NTH, 1)
void lstm_kernel(const int* __restrict__ ev,
                 const float* __restrict__ path,
                 const float* __restrict__ gate_w,
                 const float* __restrict__ gate_b,
                 float* __restrict__ hbuf,   // [2][NB][NH]
                 int* __restrict__ prog,     // [NGRP][BPG] per-producer step ctr
                 float* __restrict__ out) {  // [3][NT][NB][NH]
  __shared__ float in_s[BPB][KTOT + KTOT / 32];   // [x(t) | h(t)] padded
  __shared__ float p_s[32][NJ * BPB + 1];         // stride 257 -> conflict-free
  __shared__ float zred[NJ * BPB];
  __shared__ float c_s[BPB][UPB];

  const int bid = blockIdx.x;
  const int grp = bid >> 5;   // group = consecutive 32-block range (R12)
  const int blk = bid & 31;
  const int b0 = grp * BPB;
  const int u0 = blk * UPB;
  const int tid = threadIdx.x;
  const int jg = tid >> 5;   // 0..15: which 4-row group of gate rows
  const int ks = tid & 31;   // 0..31: which k-slice (16 x-k + 16 h-k)

  // gate_w slice:
  // w[jj][0..15]  = W[j][ks*16 .. +16)          (x half)
  // w[jj][16..31] = W[j][512 + ks*16 .. +16)    (h half)
  float w[4][2 * KHALF];
#pragma unroll
  for (int jj = 0; jj < 4; ++jj) {
    int r = jg * 4 + jj;                        // 0..63: gate*16 + uu
    int j = (r >> 4) * NH + u0 + (r & 15);      // global gate row
    const float* wx = gate_w + (size_t)j * KTOT + ks * KHALF;
    const float* wh = gate_w + (size_t)j * KTOT + NH + ks * KHALF;
#pragma unroll
    for (int kk = 0; kk < KHALF; ++kk) {
      w[jj][kk] = wx[kk];
      w[jj][KHALF + kk] = wh[kk];
    }
  }

  if (tid < BPB * UPB) c_s[tid >> 4][tid & 15] = 0.f;

  // staging maps
  const int sb2 = tid >> 7;          // x-prefetch: row 0..3
  const int off4 = (tid & 127) * 4;  // x-prefetch: 4-float chunk
  const int hrow = tid >> 5;         // h-stage (tid<128): row 0..3
  const int hc16 = (tid & 31) * 16;  // h-stage: 16-float (64B-aligned) chunk
  const size_t plane = (size_t)NT * NB * NH;
  int* myprog = prog + grp * BPG + blk;
  const int* pollp4 = prog + grp * BPG + (tid & 7) * 4;

  // pre-stage x(0) (cached loads; visibility via barrier A0 at t=0)
  {
    int e = ev[0 * NB + b0 + sb2];
    float4 v0 = *(const float4*)(path + (size_t)e * NH + off4);
    *(float4*)&in_s[sb2][fpad(off4)] = v0;
  }

#pragma unroll 1
  for (int t = 0; t < NT; ++t) {
    const bool more = (t + 1 < NT);

    // ---- wait for group's h(t) producers: 8 lanes x dwordx4 ----
    if (t > 0 && tid < 8) {
      v4i pv;
      for (;;) {
        asm volatile("global_load_dwordx4 %0, %1, off sc0 sc1\n\ts_waitcnt vmcnt(0)"
                     : "=v"(pv) : "v"(pollp4) : "memory");
        bool ok = (pv[0] >= t) && (pv[1] >= t) && (pv[2] >= t) && (pv[3] >= t);
        if ((__ballot(ok) & 0xFFull) == 0xFFull) break;
        __builtin_amdgcn_s_sleep(1);
      }
    }
    __syncthreads();   // A0: poll passed; prev step's LDS reads all complete

    // ---- stage h(t): 128 lanes x one 64B line each (4 fused dwordx4) ----
    if (tid < 128) {
      const float* hsrc =
          hbuf + ((size_t)(t & 1) * NB + (b0 + hrow)) * NH + hc16;
      float4 ha, hb, hc, hd;
      asm volatile(
          "global_load_dwordx4 %0, %4, off sc0 sc1\n\t"
          "global_load_dwordx4 %1, %4, off offset:16 sc0 sc1\n\t"
          "global_load_dwordx4 %2, %4, off offset:32 sc0 sc1\n\t"
          "global_load_dwordx4 %3, %4, off offset:48 sc0 sc1\n\t"
          "s_waitcnt vmcnt(0)"
          : "=&v"(ha), "=&v"(hb), "=&v"(hc), "=&v"(hd)
          : "v"(hsrc)
          : "memory");
      float* d = &in_s[hrow][fpad(NH + hc16)];  // 16-chunk: pad-affine
      *(float4*)(d + 0) = ha;
      *(float4*)(d + 4) = hb;
      *(float4*)(d + 8) = hc;
      *(float4*)(d + 12) = hd;
    }
    __syncthreads();   // A1: h(t) staged

    // ---- x-half GEMM: k in [ks*16, ks*16+16) from in_s x-half ----
    float acc[4][BPB];
#pragma unroll
    for (int jj = 0; jj < 4; ++jj)
#pragma unroll
      for (int bi = 0; bi < BPB; ++bi) acc[jj][bi] = 0.f;
    {
      const int fb = fpad(ks * KHALF);
#pragma unroll
      for (int bi = 0; bi < BPB; ++bi) {
        const float* inp = &in_s[bi][fb];
#pragma unroll
        for (int kk = 0; kk < KHALF; ++kk) {
          float x = inp[kk];
          acc[0][bi] = fmaf(w[0][kk], x, acc[0][bi]);
          acc[1][bi] = fmaf(w[1][kk], x, acc[1][bi]);
          acc[2][bi] = fmaf(w[2][kk], x, acc[2][bi]);
          acc[3][bi] = fmaf(w[3][kk], x, acc[3][bi]);
        }
      }
    }

    // ---- h-half GEMM: k in [512 + ks*16, +16) ----
    {
      const int fb = fpad(NH + ks * KHALF);
#pragma unroll
      for (int bi = 0; bi < BPB; ++bi) {
        const float* inp = &in_s[bi][fb];
#pragma unroll
        for (int kk = 0; kk < KHALF; ++kk) {
          float x = inp[kk];
          acc[0][bi] = fmaf(w[0][KHALF + kk], x, acc[0][bi]);
          acc[1][bi] = fmaf(w[1][KHALF + kk], x, acc[1][bi]);
          acc[2][bi] = fmaf(w[2][KHALF + kk], x, acc[2][bi]);
          acc[3][bi] = fmaf(w[3][KHALF + kk], x, acc[3][bi]);
        }
      }
    }
#pragma unroll
    for (int jj = 0; jj < 4; ++jj) {
      int r = jg * 4 + jj;
#pragma unroll
      for (int bi = 0; bi < BPB; ++bi)
        p_s[ks][r * BPB + bi] = acc[jj][bi];
    }
    __syncthreads();   // B: p_s complete; in_s x-half dead

    // ---- prefetch x(t+1) into in_s x-half (cached; off critical path) ----
    if (more) {
      int e = ev[(t + 1) * NB + b0 + sb2];
      float4 v0 = *(const float4*)(path + (size_t)e * NH + off4);
      *(float4*)&in_s[sb2][fpad(off4)] = v0;
    }

    // ---- reduce 32 k-slices + bias ----
    if (tid < NJ * BPB) {
      float s = 0.f;
#pragma unroll
      for (int k2 = 0; k2 < 32; ++k2) s += p_s[k2][tid];
      int r = tid >> 2;
      s += gate_b[(r >> 4) * NH + u0 + (r & 15)];
      zred[tid] = s;
    }
    __syncthreads();   // C: zred complete

    // ---- gates + state update + handoff (wave 0 only) ----
    if (tid < BPB * UPB) {
      int bi = tid >> 4, uu = tid & 15;
      float zi = zred[(uu) * BPB + bi];
      float zf = zred[(UPB + uu) * BPB + bi];
      float zg = zred[(2 * UPB + uu) * BPB + bi];
      float zo = zred[(3 * UPB + uu) * BPB + bi];
      float ig = 1.f / (1.f + expf(-zi));
      float fg = 1.f / (1.f + expf(-zf));
      float gg = tanhf(zg);
      float ogv = 1.f / (1.f + expf(-zo));
      float cv = fmaf(fg, c_s[bi][uu], ig * gg);
      float hvv = ogv * tanhf(cv);
      c_s[bi][uu] = cv;
      int b = b0 + bi, u = u0 + uu;
      if (more) {
        float* hdst = hbuf + ((size_t)((t + 1) & 1) * NB + b) * NH + u;
        __hip_atomic_store(hdst, hvv, __ATOMIC_RELAXED, __HIP_MEMORY_SCOPE_SYSTEM);
      }
      // announce: wave-level drain of the h stores, then per-producer word
      if (more && tid == 0) {
        asm volatile("s_waitcnt vmcnt(0)" ::: "memory");
        int nv = t + 1;
        asm volatile("global_store_dword %0, %1, off sc0 sc1"
                     :: "v"(myprog), "v"(nv) : "memory");
      }
      // output stores off the critical path (after the signal)
      size_t o0 = ((size_t)t * NB + b) * NH + u;
      out[o0] = hvv;
      out[plane + o0] = cv;
      out[2 * plane + o0] = ogv;
    }
    // no end-of-step barrier: next iteration's poll + A0 covers it
  }
}

extern "C" void kernel_launch(void* const* d_in, const int* in_sizes, int n_in,
                              void* d_out, int out_size, void* d_ws, size_t ws_size,
                              hipStream_t stream) {
  const int* ev = (const int*)d_in[0];
  const int* parents = (const int*)d_in[1];
  const float* weight = (const float*)d_in[2];
  const float* emb = (const float*)d_in[3];
  const float* gate_w = (const float*)d_in[4];
  const float* gate_b = (const float*)d_in[5];
  float* out = (float*)d_out;

  char* ws = (char*)d_ws;
  float* path = (float*)ws;
  size_t path_bytes = (size_t)NV * NH * sizeof(float);
  float* hbuf = (float*)(ws + path_bytes);
  int* prog = (int*)(ws + path_bytes + (size_t)2 * NB * NH * sizeof(float));

  init_kernel<<<(2 * NB * NH + 255) / 256, 256, 0, stream>>>(hbuf, prog);
  path_kernel<<<NV, 256, 0, stream>>>(parents, weight, emb, path);
  lstm_kernel<<<NGRP * BPG, NTH, 0, stream>>>(ev, path, gate_w, gate_b, hbuf, prog, out);
}